// Round 1
// baseline (2528.807 us; speedup 1.0000x reference)
//
#include <hip/hip_runtime.h>
#include <math.h>

#define N_NODES 20000
#define N_EDGES 240000

__device__ __forceinline__ float siluf(float v){ return v * (1.0f/(1.0f+__expf(-v))); }
__device__ __forceinline__ float sigmf(float v){ return 1.0f/(1.0f+__expf(-v)); }

// ---------------------------------------------------------------------------
// Edge geometry: sh1 (3), sh2 (5), radial basis (16)  -> EG[e][24]
// ---------------------------------------------------------------------------
__global__ void k_geom(const float* __restrict__ ev, float* __restrict__ eg){
  int e = blockIdx.x*blockDim.x + threadIdx.x;
  if (e >= N_EDGES) return;
  float x = ev[3*e+0], y = ev[3*e+1], z = ev[3*e+2];
  float r = sqrtf(x*x + y*y + z*z);
  float inv = 1.0f / fmaxf(r, 1e-12f);
  float ux = x*inv, uy = y*inv, uz = z*inv;
  float* o = eg + (size_t)e*24;
  o[0] = 1.7320508f*ux; o[1] = 1.7320508f*uy; o[2] = 1.7320508f*uz;
  o[3] = 3.8729833f*ux*uy;
  o[4] = 3.8729833f*uy*uz;
  o[5] = 1.1180340f*(3.0f*uz*uz - 1.0f);
  o[6] = 3.8729833f*uz*ux;
  o[7] = 1.9364917f*(ux*ux - uy*uy);
  const float invstep = 17.0f/3.15f;
  float t = r*invstep;
  #pragma unroll
  for (int i=0;i<16;i++){
    float d = t - (float)(i+1);
    float a = 1.0f + d, b = 1.0f - d;
    float v = 0.0f;
    if (a > 0.0f && b > 0.0f) v = 33.734292f*__expf(-1.0f/a - 1.0f/b);  // 1.14136*e^2*sqrt(16)
    o[8+i] = v;
  }
}

// ---------------------------------------------------------------------------
// Node L1: h0 = emb[x];  X0 = h0@L1_lin1_0/8 (64);  SC0 = h0@L1_sc_0/8 (144)
// 4 nodes / block of 256
// ---------------------------------------------------------------------------
__global__ void k_node_l1(const int* __restrict__ xs, const float* __restrict__ emb,
                          const float* __restrict__ Wlin, const float* __restrict__ Wsc,
                          float* __restrict__ X0, float* __restrict__ SC0){
  __shared__ float hs[4][64];
  int n0 = blockIdx.x*4;
  int t  = threadIdx.x;
  {
    int j = t>>6, k = t&63;
    hs[j][k] = emb[xs[n0+j]*64 + k];
  }
  __syncthreads();
  if (t < 64){
    float acc[4] = {};
    for (int k=0;k<64;k++){
      float wv = Wlin[k*64 + t];
      #pragma unroll
      for (int j=0;j<4;j++) acc[j] += hs[j][k]*wv;
    }
    #pragma unroll
    for (int j=0;j<4;j++) X0[(size_t)(n0+j)*64 + t] = acc[j]*0.125f;
  } else if (t < 208){
    int o = t - 64;
    float acc[4] = {};
    for (int k=0;k<64;k++){
      float wv = Wsc[k*144 + o];
      #pragma unroll
      for (int j=0;j<4;j++) acc[j] += hs[j][k]*wv;
    }
    #pragma unroll
    for (int j=0;j<4;j++) SC0[(size_t)(n0+j)*144 + o] = acc[j]*0.125f;
  }
}

// ---------------------------------------------------------------------------
// L1 edge kernel: radial 16->64->128 (W in LDS f32), m0/m1, atomic scatter
// one wave per edge
// ---------------------------------------------------------------------------
__global__ __launch_bounds__(256) void k_edge_l1(
    const int* __restrict__ ei, const float* __restrict__ eg,
    const float* __restrict__ W1, const float* __restrict__ W2,
    const float* __restrict__ X0, float* __restrict__ A0, float* __restrict__ A1){
  __shared__ float w1s[16*64];
  __shared__ float w2s[64*128];
  __shared__ float hid[4][64];
  int tid = threadIdx.x;
  for (int i=tid;i<16*64;i+=256) w1s[i] = W1[i]*0.25f;
  const float fold = 0.125f*0.28867513f;   // 1/8 * 1/sqrt(12)
  for (int i=tid;i<64*128;i+=256) w2s[i] = W2[i]*fold;
  __syncthreads();
  int lane = tid & 63, wib = tid >> 6;
  int gw = (blockIdx.x*256 + tid) >> 6;
  int nw = (gridDim.x*256) >> 6;
  for (int e = gw; e < N_EDGES; e += nw){
    const float* g = eg + (size_t)e*24;
    float acc = 0.0f;
    #pragma unroll
    for (int b=0;b<16;b++) acc += g[8+b]*w1s[b*64 + lane];
    hid[wib][lane] = siluf(acc);
    float w0 = 0.0f, w1v = 0.0f;
    #pragma unroll 8
    for (int h=0;h<64;h++){
      float hh = hid[wib][h];
      w0  += hh*w2s[h*128 + lane];
      w1v += hh*w2s[h*128 + 64 + lane];
    }
    int src = ei[e], dst = ei[N_EDGES + e];
    float x0 = X0[(size_t)src*64 + lane];
    float sx = g[0], sy = g[1], sz = g[2];
    float m0 = x0*w0, m1 = x0*w1v;
    float* a0 = A0 + (size_t)dst*64;
    float* a1 = A1 + (size_t)dst*192 + lane*3;
    atomicAdd(a0 + lane, m0);
    atomicAdd(a1 + 0, m1*sx);
    atomicAdd(a1 + 1, m1*sy);
    atomicAdd(a1 + 2, m1*sz);
  }
}

// ---------------------------------------------------------------------------
// L1 update: g0 = A0@L1_lin2_0/8 + SC0; g1 = A1@L1_lin2_1/8
// h0 = silu(g0[:128]); h1 = sigmoid(g0[128:])*g1.   8 nodes / block 256
// ---------------------------------------------------------------------------
__global__ void k_upd_l1(const float* __restrict__ A0, const float* __restrict__ A1,
                         const float* __restrict__ SC0,
                         const float* __restrict__ W20, const float* __restrict__ W21,
                         float* __restrict__ H0, float* __restrict__ H1){
  __shared__ float sig[8][16];
  __shared__ float g1s[8][48];
  int n0 = blockIdx.x*8, t = threadIdx.x;
  if (t < 144){
    float acc[8] = {};
    for (int k=0;k<64;k++){
      float wv = W20[k*144 + t];
      #pragma unroll
      for (int j=0;j<8;j++) acc[j] += A0[(size_t)(n0+j)*64 + k]*wv;
    }
    #pragma unroll
    for (int j=0;j<8;j++){
      float gg = acc[j]*0.125f + SC0[(size_t)(n0+j)*144 + t];
      if (t < 128) H0[(size_t)(n0+j)*128 + t] = siluf(gg);
      else         sig[j][t-128] = sigmf(gg);
    }
  } else if (t < 192){
    int idx = t-144, v = idx/3, k = idx%3;
    float acc[8] = {};
    for (int u=0;u<64;u++){
      float wv = W21[u*16 + v];
      #pragma unroll
      for (int j=0;j<8;j++) acc[j] += A1[(size_t)(n0+j)*192 + u*3 + k]*wv;
    }
    #pragma unroll
    for (int j=0;j<8;j++) g1s[j][idx] = acc[j]*0.125f;
  }
  __syncthreads();
  if (t >= 144 && t < 192){
    int idx = t-144, v = idx/3;
    #pragma unroll
    for (int j=0;j<8;j++) H1[(size_t)(n0+j)*48 + idx] = sig[j][v]*g1s[j][idx];
  }
}

// ---------------------------------------------------------------------------
// L2 node linears: SC0 (144), SC1 (16x3), X0 (128), X1 (16x3). 8 nodes / block 384
// ---------------------------------------------------------------------------
__global__ void k_lin_l2(const float* __restrict__ H0, const float* __restrict__ H1,
                         const float* __restrict__ Wsc0, const float* __restrict__ Wsc1,
                         const float* __restrict__ Wl0,  const float* __restrict__ Wl1,
                         float* __restrict__ SC0, float* __restrict__ SC1,
                         float* __restrict__ X0,  float* __restrict__ X1){
  int n0 = blockIdx.x*8, t = threadIdx.x;
  const float is128 = 0.08838835f;  // 1/sqrt(128)
  if (t < 144){
    float acc[8] = {};
    for (int k=0;k<128;k++){
      float wv = Wsc0[k*144 + t];
      #pragma unroll
      for (int j=0;j<8;j++) acc[j] += H0[(size_t)(n0+j)*128 + k]*wv;
    }
    #pragma unroll
    for (int j=0;j<8;j++) SC0[(size_t)(n0+j)*144 + t] = acc[j]*is128;
  } else if (t < 192){
    int idx = t-144, v = idx/3, k = idx%3;
    float acc[8] = {};
    for (int u=0;u<16;u++){
      float wv = Wsc1[u*16 + v];
      #pragma unroll
      for (int j=0;j<8;j++) acc[j] += H1[(size_t)(n0+j)*48 + u*3 + k]*wv;
    }
    #pragma unroll
    for (int j=0;j<8;j++) SC1[(size_t)(n0+j)*48 + idx] = acc[j]*0.25f;
  } else if (t < 320){
    int o = t-192;
    float acc[8] = {};
    for (int k=0;k<128;k++){
      float wv = Wl0[k*128 + o];
      #pragma unroll
      for (int j=0;j<8;j++) acc[j] += H0[(size_t)(n0+j)*128 + k]*wv;
    }
    #pragma unroll
    for (int j=0;j<8;j++) X0[(size_t)(n0+j)*128 + o] = acc[j]*is128;
  } else if (t < 368){
    int idx = t-320, v = idx/3, k = idx%3;
    float acc[8] = {};
    for (int u=0;u<16;u++){
      float wv = Wl1[u*16 + v];
      #pragma unroll
      for (int j=0;j<8;j++) acc[j] += H1[(size_t)(n0+j)*48 + u*3 + k]*wv;
    }
    #pragma unroll
    for (int j=0;j<8;j++) X1[(size_t)(n0+j)*48 + idx] = acc[j]*0.25f;
  }
}

// ---------------------------------------------------------------------------
// L2 edge kernel: radial 16->64->320 (W2 bf16 in LDS), full tensor-product
// messages, atomic scatter.  one wave per edge.
// ---------------------------------------------------------------------------
__global__ __launch_bounds__(256) void k_edge_l2(
    const int* __restrict__ ei, const float* __restrict__ eg,
    const float* __restrict__ W1, const float* __restrict__ W2,
    const float* __restrict__ X0, const float* __restrict__ X1,
    float* __restrict__ A0, float* __restrict__ A1){
  __shared__ float w1s[16*64];
  __shared__ unsigned short w2s[64*320];
  __shared__ float hid[4][64];
  int tid = threadIdx.x;
  for (int i=tid;i<16*64;i+=256) w1s[i] = W1[i]*0.25f;
  const float fold = 0.125f*0.28867513f;
  for (int i=tid;i<64*320;i+=256){
    int col = i % 320;
    float extra = 1.0f;
    if      (col >= 272 && col < 288) extra = 0.57735027f;  // 1/sqrt(3) (m0b)
    else if (col >= 288 && col < 304) extra = 0.40824829f;  // 1/sqrt(6) (m1c)
    float v = W2[i]*fold*extra;
    unsigned u = __float_as_uint(v);
    u = (u + 0x7fffu + ((u>>16)&1u)) >> 16;  // RNE to bf16
    w2s[i] = (unsigned short)u;
  }
  __syncthreads();
  int lane = tid & 63, wib = tid >> 6;
  int gw = (blockIdx.x*256 + tid) >> 6;
  int nw = (gridDim.x*256) >> 6;
  for (int e = gw; e < N_EDGES; e += nw){
    const float* g = eg + (size_t)e*24;
    float acc = 0.0f;
    #pragma unroll
    for (int b=0;b<16;b++) acc += g[8+b]*w1s[b*64 + lane];
    hid[wib][lane] = siluf(acc);
    float w0=0.f, w1v=0.f, w2v=0.f, w3v=0.f, w4v=0.f;
    #pragma unroll 4
    for (int h=0;h<64;h++){
      float hh = hid[wib][h];
      const unsigned short* row = w2s + h*320;
      w0  += hh*__uint_as_float((unsigned)row[lane      ] << 16);
      w1v += hh*__uint_as_float((unsigned)row[ 64 + lane] << 16);
      w2v += hh*__uint_as_float((unsigned)row[128 + lane] << 16);
      w3v += hh*__uint_as_float((unsigned)row[192 + lane] << 16);
      w4v += hh*__uint_as_float((unsigned)row[256 + lane] << 16);
    }
    int src = ei[e], dst = ei[N_EDGES + e];
    const float* x0p = X0 + (size_t)src*128;
    float x0a = x0p[lane], x0b = x0p[64 + lane];
    float sx = g[0], sy = g[1], sz = g[2];
    float* a0 = A0 + (size_t)dst*144;
    float* a1 = A1 + (size_t)dst*528;
    atomicAdd(a0 + lane,      x0a*w0);
    atomicAdd(a0 + 64 + lane, x0b*w1v);
    float ma = x0a*w2v, mb = x0b*w3v;
    float* p = a1 + lane*3;
    atomicAdd(p+0, ma*sx); atomicAdd(p+1, ma*sy); atomicAdd(p+2, ma*sz);
    p = a1 + (64 + lane)*3;
    atomicAdd(p+0, mb*sx); atomicAdd(p+1, mb*sy); atomicAdd(p+2, mb*sz);
    int grp = lane >> 4, v = lane & 15;
    const float* x1p = X1 + (size_t)src*48 + v*3;
    float xx = x1p[0], xy = x1p[1], xz = x1p[2];
    if (grp == 0){           // m1b: rows 128..143
      float* q = a1 + (128 + v)*3;
      atomicAdd(q+0, w4v*xx); atomicAdd(q+1, w4v*xy); atomicAdd(q+2, w4v*xz);
    } else if (grp == 1){    // m0b: A0 rows 128..143 (1/sqrt3 folded)
      float dot = xx*sx + xy*sy + xz*sz;
      atomicAdd(a0 + 128 + v, w4v*dot);
    } else if (grp == 2){    // m1c: rows 144..159 (1/sqrt6 folded)
      float cx = xy*sz - xz*sy;
      float cy = xz*sx - xx*sz;
      float cz = xx*sy - xy*sx;
      float* q = a1 + (144 + v)*3;
      atomicAdd(q+0, w4v*cx); atomicAdd(q+1, w4v*cy); atomicAdd(q+2, w4v*cz);
    } else {                 // m1d: rows 160..175 via CG121 contraction
      float s20=g[3], s21=g[4], s22=g[5], s23=g[6], s24=g[7];
      const float c1 = 0.31622777f, c2 = 0.18257419f;
      float t0 = xx*(c1*s24 - c2*s22) + xy*(c1*s20)            + xz*(c1*s23);
      float t1 = xx*(c1*s20)          + xy*(-c2*s22 - c1*s24)  + xz*(c1*s21);
      float t2 = xx*(c1*s23)          + xy*(c1*s21)            + xz*(2.0f*c2*s22);
      float* q = a1 + (160 + v)*3;
      atomicAdd(q+0, w4v*t0); atomicAdd(q+1, w4v*t1); atomicAdd(q+2, w4v*t2);
    }
  }
}

// ---------------------------------------------------------------------------
// L2 update: g0 = A0@L2_lin2_0/12 + SC0; g1 = A1@L2_lin2_1/sqrt(176) + SC1
// 8 nodes / block 256
// ---------------------------------------------------------------------------
__global__ void k_upd_l2(const float* __restrict__ A0, const float* __restrict__ A1,
                         const float* __restrict__ SC0, const float* __restrict__ SC1,
                         const float* __restrict__ W20, const float* __restrict__ W21,
                         float* __restrict__ H0, float* __restrict__ H1){
  __shared__ float sig[8][16];
  __shared__ float g1s[8][48];
  int n0 = blockIdx.x*8, t = threadIdx.x;
  if (t < 144){
    float acc[8] = {};
    for (int k=0;k<144;k++){
      float wv = W20[k*144 + t];
      #pragma unroll
      for (int j=0;j<8;j++) acc[j] += A0[(size_t)(n0+j)*144 + k]*wv;
    }
    #pragma unroll
    for (int j=0;j<8;j++){
      float gg = acc[j]*(1.0f/12.0f) + SC0[(size_t)(n0+j)*144 + t];
      if (t < 128) H0[(size_t)(n0+j)*128 + t] = siluf(gg);
      else         sig[j][t-128] = sigmf(gg);
    }
  } else if (t < 192){
    int idx = t-144, v = idx/3, k = idx%3;
    float acc[8] = {};
    for (int u=0;u<176;u++){
      float wv = W21[u*16 + v];
      #pragma unroll
      for (int j=0;j<8;j++) acc[j] += A1[(size_t)(n0+j)*528 + u*3 + k]*wv;
    }
    #pragma unroll
    for (int j=0;j<8;j++) g1s[j][idx] = acc[j]*0.075377836f + SC1[(size_t)(n0+j)*48 + idx];
  }
  __syncthreads();
  if (t >= 144 && t < 192){
    int idx = t-144, v = idx/3;
    #pragma unroll
    for (int j=0;j<8;j++) H1[(size_t)(n0+j)*48 + idx] = sig[j][v]*g1s[j][idx];
  }
}

// ---------------------------------------------------------------------------
// LO node linears: SCO (4), X0 (128), X1 (16x3). 8 nodes / block 256
// ---------------------------------------------------------------------------
__global__ void k_lin_lo(const float* __restrict__ H0, const float* __restrict__ H1,
                         const float* __restrict__ Wsc0,
                         const float* __restrict__ Wl0, const float* __restrict__ Wl1,
                         float* __restrict__ SCO, float* __restrict__ X0, float* __restrict__ X1){
  int n0 = blockIdx.x*8, t = threadIdx.x;
  const float is128 = 0.08838835f;
  if (t < 4){
    float acc[8] = {};
    for (int k=0;k<128;k++){
      float wv = Wsc0[k*4 + t];
      #pragma unroll
      for (int j=0;j<8;j++) acc[j] += H0[(size_t)(n0+j)*128 + k]*wv;
    }
    #pragma unroll
    for (int j=0;j<8;j++) SCO[(size_t)(n0+j)*4 + t] = acc[j]*is128;
  } else if (t < 132){
    int o = t-4;
    float acc[8] = {};
    for (int k=0;k<128;k++){
      float wv = Wl0[k*128 + o];
      #pragma unroll
      for (int j=0;j<8;j++) acc[j] += H0[(size_t)(n0+j)*128 + k]*wv;
    }
    #pragma unroll
    for (int j=0;j<8;j++) X0[(size_t)(n0+j)*128 + o] = acc[j]*is128;
  } else if (t < 180){
    int idx = t-132, v = idx/3, k = idx%3;
    float acc[8] = {};
    for (int u=0;u<16;u++){
      float wv = Wl1[u*16 + v];
      #pragma unroll
      for (int j=0;j<8;j++) acc[j] += H1[(size_t)(n0+j)*48 + u*3 + k]*wv;
    }
    #pragma unroll
    for (int j=0;j<8;j++) X1[(size_t)(n0+j)*48 + idx] = acc[j]*0.25f;
  }
}

// ---------------------------------------------------------------------------
// LO edge kernel: radial 16->64->144 (LDS f32, padded to 192 cols), m0a/m0b.
// ---------------------------------------------------------------------------
__global__ __launch_bounds__(256) void k_edge_lo(
    const int* __restrict__ ei, const float* __restrict__ eg,
    const float* __restrict__ W1, const float* __restrict__ W2,
    const float* __restrict__ X0, const float* __restrict__ X1,
    float* __restrict__ A0){
  __shared__ float w1s[16*64];
  __shared__ float w2s[64*192];
  __shared__ float hid[4][64];
  int tid = threadIdx.x;
  for (int i=tid;i<16*64;i+=256) w1s[i] = W1[i]*0.25f;
  const float fold = 0.125f*0.28867513f;
  for (int i=tid;i<64*192;i+=256){
    int row = i / 192, col = i % 192;
    float v = 0.0f;
    if (col < 144){
      float extra = (col >= 128) ? 0.57735027f : 1.0f;   // m0b 1/sqrt(3)
      v = W2[row*144 + col]*fold*extra;
    }
    w2s[i] = v;
  }
  __syncthreads();
  int lane = tid & 63, wib = tid >> 6;
  int gw = (blockIdx.x*256 + tid) >> 6;
  int nw = (gridDim.x*256) >> 6;
  for (int e = gw; e < N_EDGES; e += nw){
    const float* g = eg + (size_t)e*24;
    float acc = 0.0f;
    #pragma unroll
    for (int b=0;b<16;b++) acc += g[8+b]*w1s[b*64 + lane];
    hid[wib][lane] = siluf(acc);
    float w0=0.f, w1v=0.f, w2v=0.f;
    #pragma unroll 8
    for (int h=0;h<64;h++){
      float hh = hid[wib][h];
      w0  += hh*w2s[h*192 + lane];
      w1v += hh*w2s[h*192 + 64 + lane];
      w2v += hh*w2s[h*192 + 128 + lane];
    }
    int src = ei[e], dst = ei[N_EDGES + e];
    const float* x0p = X0 + (size_t)src*128;
    float x0a = x0p[lane], x0b = x0p[64 + lane];
    float* a0 = A0 + (size_t)dst*144;
    atomicAdd(a0 + lane,      x0a*w0);
    atomicAdd(a0 + 64 + lane, x0b*w1v);
    if (lane < 16){
      const float* x1p = X1 + (size_t)src*48 + lane*3;
      float dot = x1p[0]*g[0] + x1p[1]*g[1] + x1p[2]*g[2];
      atomicAdd(a0 + 128 + lane, w2v*dot);
    }
  }
}

// ---------------------------------------------------------------------------
// Final: out = A0@LO_lin2_0/12 + SCO   (N,4)
// ---------------------------------------------------------------------------
__global__ void k_final(const float* __restrict__ A0, const float* __restrict__ SCO,
                        const float* __restrict__ W, float* __restrict__ out){
  int i = blockIdx.x*blockDim.x + threadIdx.x;
  if (i >= N_NODES*4) return;
  int n = i >> 2, c = i & 3;
  const float* a0 = A0 + (size_t)n*144;
  float acc = 0.0f;
  for (int k=0;k<144;k++) acc += a0[k]*W[k*4 + c];
  out[i] = acc*(1.0f/12.0f) + SCO[i];
}

// ---------------------------------------------------------------------------
extern "C" void kernel_launch(void* const* d_in, const int* in_sizes, int n_in,
                              void* d_out, int out_size, void* d_ws, size_t ws_size,
                              hipStream_t stream) {
  const int*   x   = (const int*)  d_in[0];
  const int*   ei  = (const int*)  d_in[1];
  const float* ev  = (const float*)d_in[2];
  const float* emb = (const float*)d_in[3];
  const float* L1_lin1_0 = (const float*)d_in[4];
  const float* L1_W1     = (const float*)d_in[5];
  const float* L1_W2     = (const float*)d_in[6];
  const float* L1_lin2_0 = (const float*)d_in[7];
  const float* L1_lin2_1 = (const float*)d_in[8];
  const float* L1_sc_0   = (const float*)d_in[9];
  const float* L2_lin1_0 = (const float*)d_in[10];
  const float* L2_lin1_1 = (const float*)d_in[11];
  const float* L2_W1     = (const float*)d_in[12];
  const float* L2_W2     = (const float*)d_in[13];
  const float* L2_lin2_0 = (const float*)d_in[14];
  const float* L2_lin2_1 = (const float*)d_in[15];
  const float* L2_sc_0   = (const float*)d_in[16];
  const float* L2_sc_1   = (const float*)d_in[17];
  const float* LO_lin1_0 = (const float*)d_in[18];
  const float* LO_lin1_1 = (const float*)d_in[19];
  const float* LO_W1     = (const float*)d_in[20];
  const float* LO_W2     = (const float*)d_in[21];
  const float* LO_lin2_0 = (const float*)d_in[22];
  const float* LO_sc_0   = (const float*)d_in[23];
  float* out = (float*)d_out;

  float* EG  = (float*)d_ws;                        // E*24
  float* X0  = EG  + (size_t)N_EDGES*24;            // N*128
  float* X1  = X0  + (size_t)N_NODES*128;           // N*48
  float* SC0 = X1  + (size_t)N_NODES*48;            // N*144
  float* SC1 = SC0 + (size_t)N_NODES*144;           // N*48
  float* A0  = SC1 + (size_t)N_NODES*48;            // N*144
  float* A1  = A0  + (size_t)N_NODES*144;           // N*528
  float* H0  = A1  + (size_t)N_NODES*528;           // N*128
  float* H1  = H0  + (size_t)N_NODES*128;           // N*48

  k_geom<<<(N_EDGES+255)/256, 256, 0, stream>>>(ev, EG);
  k_node_l1<<<N_NODES/4, 256, 0, stream>>>(x, emb, L1_lin1_0, L1_sc_0, X0, SC0);

  hipMemsetAsync(A0, 0, (size_t)N_NODES*64*4,  stream);
  hipMemsetAsync(A1, 0, (size_t)N_NODES*192*4, stream);
  k_edge_l1<<<1024, 256, 0, stream>>>(ei, EG, L1_W1, L1_W2, X0, A0, A1);
  k_upd_l1<<<N_NODES/8, 256, 0, stream>>>(A0, A1, SC0, L1_lin2_0, L1_lin2_1, H0, H1);

  k_lin_l2<<<N_NODES/8, 384, 0, stream>>>(H0, H1, L2_sc_0, L2_sc_1, L2_lin1_0, L2_lin1_1,
                                          SC0, SC1, X0, X1);
  hipMemsetAsync(A0, 0, (size_t)N_NODES*144*4, stream);
  hipMemsetAsync(A1, 0, (size_t)N_NODES*528*4, stream);
  k_edge_l2<<<1024, 256, 0, stream>>>(ei, EG, L2_W1, L2_W2, X0, X1, A0, A1);
  k_upd_l2<<<N_NODES/8, 256, 0, stream>>>(A0, A1, SC0, SC1, L2_lin2_0, L2_lin2_1, H0, H1);

  // SCO (N*4) reuses SC1 storage (SC1 fully consumed by k_upd_l2)
  k_lin_lo<<<N_NODES/8, 256, 0, stream>>>(H0, H1, LO_sc_0, LO_lin1_0, LO_lin1_1, SC1, X0, X1);
  hipMemsetAsync(A0, 0, (size_t)N_NODES*144*4, stream);
  k_edge_lo<<<1024, 256, 0, stream>>>(ei, EG, LO_W1, LO_W2, X0, X1, A0);
  k_final<<<(N_NODES*4+255)/256, 256, 0, stream>>>(A0, SC1, LO_lin2_0, out);
}

// Round 3
// 912.306 us; speedup vs baseline: 2.7719x; 2.7719x over previous
//
#include <hip/hip_runtime.h>
#include <math.h>

#define N_NODES 20000
#define N_EDGES 240000

typedef _Float16 half2_t __attribute__((ext_vector_type(2)));
typedef unsigned uint4v __attribute__((ext_vector_type(4)));

__device__ __forceinline__ float siluf(float v){ return v * (1.0f/(1.0f+__expf(-v))); }
__device__ __forceinline__ float sigmf(float v){ return 1.0f/(1.0f+__expf(-v)); }

__device__ __forceinline__ unsigned pack_h2(float a, float b){
  half2_t h; h.x = (_Float16)a; h.y = (_Float16)b;
  return __builtin_bit_cast(unsigned, h);
}
__device__ __forceinline__ float dot2f(unsigned w, unsigned h, float acc){
#if __has_builtin(__builtin_amdgcn_fdot2)
  return __builtin_amdgcn_fdot2(__builtin_bit_cast(half2_t,w),
                                __builtin_bit_cast(half2_t,h), acc, false);
#else
  half2_t a = __builtin_bit_cast(half2_t,w), b = __builtin_bit_cast(half2_t,h);
  return acc + (float)a.x*(float)b.x + (float)a.y*(float)b.y;
#endif
}
__device__ __forceinline__ float dot8f(uint4v w, const unsigned* hq, float acc){
  acc = dot2f(w.x, hq[0], acc);
  acc = dot2f(w.y, hq[1], acc);
  acc = dot2f(w.z, hq[2], acc);
  return dot2f(w.w, hq[3], acc);
}

// ---------------------------------------------------------------------------
// CSR build: count -> scan -> scatter
// ---------------------------------------------------------------------------
__global__ void k_count(const int* __restrict__ ei, int* __restrict__ cnt){
  int e = blockIdx.x*blockDim.x + threadIdx.x;
  if (e < N_EDGES) atomicAdd(&cnt[ei[N_EDGES + e]], 1);
}

__global__ void k_scan(const int* __restrict__ cnt, int* __restrict__ off, int* __restrict__ pos){
  __shared__ int part[1024];
  int t = threadIdx.x;
  int c[20]; int s = 0;
  #pragma unroll
  for (int j=0;j<20;j++){
    int idx = t*20 + j;
    int v = (idx < N_NODES) ? cnt[idx] : 0;
    c[j] = s; s += v;
  }
  part[t] = s;
  __syncthreads();
  for (int d=1; d<1024; d<<=1){
    int add = (t>=d) ? part[t-d] : 0;
    __syncthreads();
    part[t] += add;
    __syncthreads();
  }
  int excl = part[t] - s;
  #pragma unroll
  for (int j=0;j<20;j++){
    int idx = t*20 + j;
    if (idx < N_NODES){ off[idx] = excl + c[j]; pos[idx] = excl + c[j]; }
  }
  if (t == 1023) off[N_NODES] = part[1023];
}

__global__ void k_scatter(const int* __restrict__ ei, int* __restrict__ pos,
                          int* __restrict__ perm, int* __restrict__ srcs){
  int e = blockIdx.x*blockDim.x + threadIdx.x;
  if (e >= N_EDGES) return;
  int d = ei[N_EDGES + e];
  int p = atomicAdd(&pos[d], 1);
  perm[e] = p;
  srcs[p] = ei[e];
}

// ---------------------------------------------------------------------------
// Edge geometry in CSR order
// ---------------------------------------------------------------------------
__global__ void k_geom(const float* __restrict__ ev, const int* __restrict__ perm,
                       float* __restrict__ eg){
  int e = blockIdx.x*blockDim.x + threadIdx.x;
  if (e >= N_EDGES) return;
  float x = ev[3*e+0], y = ev[3*e+1], z = ev[3*e+2];
  float r = sqrtf(x*x + y*y + z*z);
  float inv = 1.0f / fmaxf(r, 1e-12f);
  float ux = x*inv, uy = y*inv, uz = z*inv;
  float* o = eg + (size_t)perm[e]*24;
  o[0] = 1.7320508f*ux; o[1] = 1.7320508f*uy; o[2] = 1.7320508f*uz;
  o[3] = 3.8729833f*ux*uy;
  o[4] = 3.8729833f*uy*uz;
  o[5] = 1.1180340f*(3.0f*uz*uz - 1.0f);
  o[6] = 3.8729833f*uz*ux;
  o[7] = 1.9364917f*(ux*ux - uy*uy);
  const float invstep = 17.0f/3.15f;
  float t = r*invstep;
  #pragma unroll
  for (int i=0;i<16;i++){
    float d = t - (float)(i+1);
    float a = 1.0f + d, b = 1.0f - d;
    float v = 0.0f;
    if (a > 0.0f && b > 0.0f) v = 33.734292f*__expf(-1.0f/a - 1.0f/b);
    o[8+i] = v;
  }
}

// ---------------------------------------------------------------------------
// Node L1
// ---------------------------------------------------------------------------
__global__ void k_node_l1(const int* __restrict__ xs, const float* __restrict__ emb,
                          const float* __restrict__ Wlin, const float* __restrict__ Wsc,
                          float* __restrict__ X0, float* __restrict__ SC0){
  __shared__ float hs[4][64];
  int n0 = blockIdx.x*4;
  int t  = threadIdx.x;
  {
    int j = t>>6, k = t&63;
    hs[j][k] = emb[xs[n0+j]*64 + k];
  }
  __syncthreads();
  if (t < 64){
    float acc[4] = {};
    for (int k=0;k<64;k++){
      float wv = Wlin[k*64 + t];
      #pragma unroll
      for (int j=0;j<4;j++) acc[j] += hs[j][k]*wv;
    }
    #pragma unroll
    for (int j=0;j<4;j++) X0[(size_t)(n0+j)*64 + t] = acc[j]*0.125f;
  } else if (t < 208){
    int o = t - 64;
    float acc[4] = {};
    for (int k=0;k<64;k++){
      float wv = Wsc[k*144 + o];
      #pragma unroll
      for (int j=0;j<4;j++) acc[j] += hs[j][k]*wv;
    }
    #pragma unroll
    for (int j=0;j<4;j++) SC0[(size_t)(n0+j)*144 + o] = acc[j]*0.125f;
  }
}

// ---------------------------------------------------------------------------
// L1 edge-gather: one wave per dst node, register accumulation, no atomics
// ---------------------------------------------------------------------------
__global__ __launch_bounds__(256) void k_edge_l1(
    const int* __restrict__ off, const int* __restrict__ srcs, const float* __restrict__ eg,
    const float* __restrict__ W1, const float* __restrict__ W2,
    const float* __restrict__ X0, float* __restrict__ A0, float* __restrict__ A1){
  __shared__ float w1s[16*64];
  __shared__ uint4v w2q[8*128];
  __shared__ unsigned hidp[4][32];
  int tid = threadIdx.x;
  for (int i=tid;i<16*64;i+=256) w1s[i] = W1[i]*0.25f;
  const float fold = 0.125f*0.28867513f;   // 1/8 * 1/sqrt(12)
  for (int i=tid;i<8*128;i+=256){
    int q = i/128, col = i%128;
    uint4v wv;
    wv.x = pack_h2(W2[(8*q+0)*128+col]*fold, W2[(8*q+1)*128+col]*fold);
    wv.y = pack_h2(W2[(8*q+2)*128+col]*fold, W2[(8*q+3)*128+col]*fold);
    wv.z = pack_h2(W2[(8*q+4)*128+col]*fold, W2[(8*q+5)*128+col]*fold);
    wv.w = pack_h2(W2[(8*q+6)*128+col]*fold, W2[(8*q+7)*128+col]*fold);
    w2q[i] = wv;
  }
  __syncthreads();
  int lane = tid & 63, wib = tid >> 6;
  int gw = (blockIdx.x*256 + tid) >> 6;
  int nw = (gridDim.x*256) >> 6;
  for (int n = gw; n < N_NODES; n += nw){
    int ib = off[n], ie = off[n+1];
    float a0a = 0.0f, a1a[3] = {0,0,0};
    for (int i = ib; i < ie; i++){
      const float* g = eg + (size_t)i*24;
      int src = srcs[i];
      float x0 = X0[(size_t)src*64 + lane];
      float acc = 0.0f;
      #pragma unroll
      for (int b=0;b<16;b++) acc = fmaf(g[8+b], w1s[b*64 + lane], acc);
      float hv = siluf(acc);
      float hp2 = __shfl_xor(hv, 1);
      if ((lane & 1) == 0) hidp[wib][lane>>1] = pack_h2(hv, hp2);
      float w0 = 0.0f, w1v = 0.0f;
      #pragma unroll
      for (int q=0;q<8;q++){
        unsigned hq[4] = {hidp[wib][4*q], hidp[wib][4*q+1], hidp[wib][4*q+2], hidp[wib][4*q+3]};
        w0  = dot8f(w2q[q*128 + lane],      hq, w0);
        w1v = dot8f(w2q[q*128 + 64 + lane], hq, w1v);
      }
      float m0 = x0*w0, m1 = x0*w1v;
      a0a += m0;
      a1a[0] += m1*g[0]; a1a[1] += m1*g[1]; a1a[2] += m1*g[2];
    }
    A0[(size_t)n*64 + lane] = a0a;
    float* p = A1 + (size_t)n*192 + lane*3;
    p[0] = a1a[0]; p[1] = a1a[1]; p[2] = a1a[2];
  }
}

// ---------------------------------------------------------------------------
// L1 update
// ---------------------------------------------------------------------------
__global__ void k_upd_l1(const float* __restrict__ A0, const float* __restrict__ A1,
                         const float* __restrict__ SC0,
                         const float* __restrict__ W20, const float* __restrict__ W21,
                         float* __restrict__ H0, float* __restrict__ H1){
  __shared__ float sig[8][16];
  __shared__ float g1s[8][48];
  int n0 = blockIdx.x*8, t = threadIdx.x;
  if (t < 144){
    float acc[8] = {};
    for (int k=0;k<64;k++){
      float wv = W20[k*144 + t];
      #pragma unroll
      for (int j=0;j<8;j++) acc[j] += A0[(size_t)(n0+j)*64 + k]*wv;
    }
    #pragma unroll
    for (int j=0;j<8;j++){
      float gg = acc[j]*0.125f + SC0[(size_t)(n0+j)*144 + t];
      if (t < 128) H0[(size_t)(n0+j)*128 + t] = siluf(gg);
      else         sig[j][t-128] = sigmf(gg);
    }
  } else if (t < 192){
    int idx = t-144, v = idx/3, k = idx%3;
    float acc[8] = {};
    for (int u=0;u<64;u++){
      float wv = W21[u*16 + v];
      #pragma unroll
      for (int j=0;j<8;j++) acc[j] += A1[(size_t)(n0+j)*192 + u*3 + k]*wv;
    }
    #pragma unroll
    for (int j=0;j<8;j++) g1s[j][idx] = acc[j]*0.125f;
  }
  __syncthreads();
  if (t >= 144 && t < 192){
    int idx = t-144, v = idx/3;
    #pragma unroll
    for (int j=0;j<8;j++) H1[(size_t)(n0+j)*48 + idx] = sig[j][v]*g1s[j][idx];
  }
}

// ---------------------------------------------------------------------------
// L2 node linears
// ---------------------------------------------------------------------------
__global__ void k_lin_l2(const float* __restrict__ H0, const float* __restrict__ H1,
                         const float* __restrict__ Wsc0, const float* __restrict__ Wsc1,
                         const float* __restrict__ Wl0,  const float* __restrict__ Wl1,
                         float* __restrict__ SC0, float* __restrict__ SC1,
                         float* __restrict__ X0,  float* __restrict__ X1){
  int n0 = blockIdx.x*8, t = threadIdx.x;
  const float is128 = 0.08838835f;
  if (t < 144){
    float acc[8] = {};
    for (int k=0;k<128;k++){
      float wv = Wsc0[k*144 + t];
      #pragma unroll
      for (int j=0;j<8;j++) acc[j] += H0[(size_t)(n0+j)*128 + k]*wv;
    }
    #pragma unroll
    for (int j=0;j<8;j++) SC0[(size_t)(n0+j)*144 + t] = acc[j]*is128;
  } else if (t < 192){
    int idx = t-144, v = idx/3, k = idx%3;
    float acc[8] = {};
    for (int u=0;u<16;u++){
      float wv = Wsc1[u*16 + v];
      #pragma unroll
      for (int j=0;j<8;j++) acc[j] += H1[(size_t)(n0+j)*48 + u*3 + k]*wv;
    }
    #pragma unroll
    for (int j=0;j<8;j++) SC1[(size_t)(n0+j)*48 + idx] = acc[j]*0.25f;
  } else if (t < 320){
    int o = t-192;
    float acc[8] = {};
    for (int k=0;k<128;k++){
      float wv = Wl0[k*128 + o];
      #pragma unroll
      for (int j=0;j<8;j++) acc[j] += H0[(size_t)(n0+j)*128 + k]*wv;
    }
    #pragma unroll
    for (int j=0;j<8;j++) X0[(size_t)(n0+j)*128 + o] = acc[j]*is128;
  } else if (t < 368){
    int idx = t-320, v = idx/3, k = idx%3;
    float acc[8] = {};
    for (int u=0;u<16;u++){
      float wv = Wl1[u*16 + v];
      #pragma unroll
      for (int j=0;j<8;j++) acc[j] += H1[(size_t)(n0+j)*48 + u*3 + k]*wv;
    }
    #pragma unroll
    for (int j=0;j<8;j++) X1[(size_t)(n0+j)*48 + idx] = acc[j]*0.25f;
  }
}

// ---------------------------------------------------------------------------
// L2 edge-gather: one wave per dst node, full tensor product, no atomics
// ---------------------------------------------------------------------------
__global__ __launch_bounds__(256) void k_edge_l2(
    const int* __restrict__ off, const int* __restrict__ srcs, const float* __restrict__ eg,
    const float* __restrict__ W1, const float* __restrict__ W2,
    const float* __restrict__ X0, const float* __restrict__ X1,
    float* __restrict__ A0, float* __restrict__ A1){
  __shared__ float w1s[16*64];
  __shared__ uint4v w2q[8*320];
  __shared__ unsigned hidp[4][32];
  int tid = threadIdx.x;
  for (int i=tid;i<16*64;i+=256) w1s[i] = W1[i]*0.25f;
  const float fold = 0.125f*0.28867513f;
  for (int i=tid;i<8*320;i+=256){
    int q = i/320, col = i%320;
    float extra = 1.0f;
    if      (col >= 272 && col < 288) extra = 0.57735027f;  // 1/sqrt(3) (m0b)
    else if (col >= 288 && col < 304) extra = 0.40824829f;  // 1/sqrt(6) (m1c)
    float fe = fold*extra;
    uint4v wv;
    wv.x = pack_h2(W2[(8*q+0)*320+col]*fe, W2[(8*q+1)*320+col]*fe);
    wv.y = pack_h2(W2[(8*q+2)*320+col]*fe, W2[(8*q+3)*320+col]*fe);
    wv.z = pack_h2(W2[(8*q+4)*320+col]*fe, W2[(8*q+5)*320+col]*fe);
    wv.w = pack_h2(W2[(8*q+6)*320+col]*fe, W2[(8*q+7)*320+col]*fe);
    w2q[i] = wv;
  }
  __syncthreads();
  int lane = tid & 63, wib = tid >> 6;
  int grp = lane >> 4, v = lane & 15;
  int gw = (blockIdx.x*256 + tid) >> 6;
  int nw = (gridDim.x*256) >> 6;
  for (int n = gw; n < N_NODES; n += nw){
    int ib = off[n], ie = off[n+1];
    float a0a=0.f, a0b=0.f, a0c=0.f;
    float a1a[3]={0,0,0}, a1b[3]={0,0,0}, a1g[3]={0,0,0};
    for (int i = ib; i < ie; i++){
      const float* g = eg + (size_t)i*24;
      int src = srcs[i];
      const float* x0p = X0 + (size_t)src*128;
      float x0a = x0p[lane], x0b = x0p[64 + lane];
      const float* x1p = X1 + (size_t)src*48 + v*3;
      float xx = x1p[0], xy = x1p[1], xz = x1p[2];
      float acc = 0.0f;
      #pragma unroll
      for (int b=0;b<16;b++) acc = fmaf(g[8+b], w1s[b*64 + lane], acc);
      float hv = siluf(acc);
      float hp2 = __shfl_xor(hv, 1);
      if ((lane & 1) == 0) hidp[wib][lane>>1] = pack_h2(hv, hp2);
      float w0=0.f, w1v=0.f, w2v=0.f, w3v=0.f, w4v=0.f;
      #pragma unroll
      for (int q=0;q<8;q++){
        unsigned hq[4] = {hidp[wib][4*q], hidp[wib][4*q+1], hidp[wib][4*q+2], hidp[wib][4*q+3]};
        const uint4v* base = w2q + q*320;
        w0  = dot8f(base[lane],       hq, w0);
        w1v = dot8f(base[ 64 + lane], hq, w1v);
        w2v = dot8f(base[128 + lane], hq, w2v);
        w3v = dot8f(base[192 + lane], hq, w3v);
        w4v = dot8f(base[256 + lane], hq, w4v);
      }
      float sx = g[0], sy = g[1], sz = g[2];
      a0a += x0a*w0;
      a0b += x0b*w1v;
      float ma = x0a*w2v, mb = x0b*w3v;
      a1a[0] += ma*sx; a1a[1] += ma*sy; a1a[2] += ma*sz;
      a1b[0] += mb*sx; a1b[1] += mb*sy; a1b[2] += mb*sz;
      if (grp == 0){           // m1b
        a1g[0] += w4v*xx; a1g[1] += w4v*xy; a1g[2] += w4v*xz;
      } else if (grp == 1){    // m0b (1/sqrt3 folded)
        a0c += w4v*(xx*sx + xy*sy + xz*sz);
      } else if (grp == 2){    // m1c (1/sqrt6 folded)
        a1g[0] += w4v*(xy*sz - xz*sy);
        a1g[1] += w4v*(xz*sx - xx*sz);
        a1g[2] += w4v*(xx*sy - xy*sx);
      } else {                 // m1d via CG121
        float s20=g[3], s21=g[4], s22=g[5], s23=g[6], s24=g[7];
        const float c1 = 0.31622777f, c2 = 0.18257419f;
        a1g[0] += w4v*(xx*(c1*s24 - c2*s22) + xy*(c1*s20)           + xz*(c1*s23));
        a1g[1] += w4v*(xx*(c1*s20)          + xy*(-c2*s22 - c1*s24) + xz*(c1*s21));
        a1g[2] += w4v*(xx*(c1*s23)          + xy*(c1*s21)           + xz*(2.0f*c2*s22));
      }
    }
    float* a0 = A0 + (size_t)n*144;
    float* a1 = A1 + (size_t)n*528;
    a0[lane] = a0a;
    a0[64 + lane] = a0b;
    if (grp == 1) a0[128 + v] = a0c;
    float* p = a1 + lane*3;
    p[0] = a1a[0]; p[1] = a1a[1]; p[2] = a1a[2];
    p = a1 + (64 + lane)*3;
    p[0] = a1b[0]; p[1] = a1b[1]; p[2] = a1b[2];
    int gbase = (grp == 0) ? 128 : (grp == 2) ? 144 : (grp == 3) ? 160 : -1;
    if (gbase >= 0){
      p = a1 + (gbase + v)*3;
      p[0] = a1g[0]; p[1] = a1g[1]; p[2] = a1g[2];
    }
  }
}

// ---------------------------------------------------------------------------
// L2 update
// ---------------------------------------------------------------------------
__global__ void k_upd_l2(const float* __restrict__ A0, const float* __restrict__ A1,
                         const float* __restrict__ SC0, const float* __restrict__ SC1,
                         const float* __restrict__ W20, const float* __restrict__ W21,
                         float* __restrict__ H0, float* __restrict__ H1){
  __shared__ float sig[8][16];
  __shared__ float g1s[8][48];
  int n0 = blockIdx.x*8, t = threadIdx.x;
  if (t < 144){
    float acc[8] = {};
    for (int k=0;k<144;k++){
      float wv = W20[k*144 + t];
      #pragma unroll
      for (int j=0;j<8;j++) acc[j] += A0[(size_t)(n0+j)*144 + k]*wv;
    }
    #pragma unroll
    for (int j=0;j<8;j++){
      float gg = acc[j]*(1.0f/12.0f) + SC0[(size_t)(n0+j)*144 + t];
      if (t < 128) H0[(size_t)(n0+j)*128 + t] = siluf(gg);
      else         sig[j][t-128] = sigmf(gg);
    }
  } else if (t < 192){
    int idx = t-144, v = idx/3, k = idx%3;
    float acc[8] = {};
    for (int u=0;u<176;u++){
      float wv = W21[u*16 + v];
      #pragma unroll
      for (int j=0;j<8;j++) acc[j] += A1[(size_t)(n0+j)*528 + u*3 + k]*wv;
    }
    #pragma unroll
    for (int j=0;j<8;j++) g1s[j][idx] = acc[j]*0.075377836f + SC1[(size_t)(n0+j)*48 + idx];
  }
  __syncthreads();
  if (t >= 144 && t < 192){
    int idx = t-144, v = idx/3;
    #pragma unroll
    for (int j=0;j<8;j++) H1[(size_t)(n0+j)*48 + idx] = sig[j][v]*g1s[j][idx];
  }
}

// ---------------------------------------------------------------------------
// LO node linears
// ---------------------------------------------------------------------------
__global__ void k_lin_lo(const float* __restrict__ H0, const float* __restrict__ H1,
                         const float* __restrict__ Wsc0,
                         const float* __restrict__ Wl0, const float* __restrict__ Wl1,
                         float* __restrict__ SCO, float* __restrict__ X0, float* __restrict__ X1){
  int n0 = blockIdx.x*8, t = threadIdx.x;
  const float is128 = 0.08838835f;
  if (t < 4){
    float acc[8] = {};
    for (int k=0;k<128;k++){
      float wv = Wsc0[k*4 + t];
      #pragma unroll
      for (int j=0;j<8;j++) acc[j] += H0[(size_t)(n0+j)*128 + k]*wv;
    }
    #pragma unroll
    for (int j=0;j<8;j++) SCO[(size_t)(n0+j)*4 + t] = acc[j]*is128;
  } else if (t < 132){
    int o = t-4;
    float acc[8] = {};
    for (int k=0;k<128;k++){
      float wv = Wl0[k*128 + o];
      #pragma unroll
      for (int j=0;j<8;j++) acc[j] += H0[(size_t)(n0+j)*128 + k]*wv;
    }
    #pragma unroll
    for (int j=0;j<8;j++) X0[(size_t)(n0+j)*128 + o] = acc[j]*is128;
  } else if (t < 180){
    int idx = t-132, v = idx/3, k = idx%3;
    float acc[8] = {};
    for (int u=0;u<16;u++){
      float wv = Wl1[u*16 + v];
      #pragma unroll
      for (int j=0;j<8;j++) acc[j] += H1[(size_t)(n0+j)*48 + u*3 + k]*wv;
    }
    #pragma unroll
    for (int j=0;j<8;j++) X1[(size_t)(n0+j)*48 + idx] = acc[j]*0.25f;
  }
}

// ---------------------------------------------------------------------------
// LO edge-gather
// ---------------------------------------------------------------------------
__global__ __launch_bounds__(256) void k_edge_lo(
    const int* __restrict__ off, const int* __restrict__ srcs, const float* __restrict__ eg,
    const float* __restrict__ W1, const float* __restrict__ W2,
    const float* __restrict__ X0, const float* __restrict__ X1,
    float* __restrict__ A0){
  __shared__ float w1s[16*64];
  __shared__ uint4v w2q[8*144];
  __shared__ unsigned hidp[4][32];
  int tid = threadIdx.x;
  for (int i=tid;i<16*64;i+=256) w1s[i] = W1[i]*0.25f;
  const float fold = 0.125f*0.28867513f;
  for (int i=tid;i<8*144;i+=256){
    int q = i/144, col = i%144;
    float fe = fold * ((col >= 128) ? 0.57735027f : 1.0f);   // m0b 1/sqrt(3)
    uint4v wv;
    wv.x = pack_h2(W2[(8*q+0)*144+col]*fe, W2[(8*q+1)*144+col]*fe);
    wv.y = pack_h2(W2[(8*q+2)*144+col]*fe, W2[(8*q+3)*144+col]*fe);
    wv.z = pack_h2(W2[(8*q+4)*144+col]*fe, W2[(8*q+5)*144+col]*fe);
    wv.w = pack_h2(W2[(8*q+6)*144+col]*fe, W2[(8*q+7)*144+col]*fe);
    w2q[i] = wv;
  }
  __syncthreads();
  int lane = tid & 63, wib = tid >> 6, v = lane & 15;
  int gw = (blockIdx.x*256 + tid) >> 6;
  int nw = (gridDim.x*256) >> 6;
  for (int n = gw; n < N_NODES; n += nw){
    int ib = off[n], ie = off[n+1];
    float a0a = 0.f, a0b = 0.f, a0c = 0.f;
    for (int i = ib; i < ie; i++){
      const float* g = eg + (size_t)i*24;
      int src = srcs[i];
      const float* x0p = X0 + (size_t)src*128;
      float x0a = x0p[lane], x0b = x0p[64 + lane];
      const float* x1p = X1 + (size_t)src*48 + v*3;
      float dot = x1p[0]*g[0] + x1p[1]*g[1] + x1p[2]*g[2];
      float acc = 0.0f;
      #pragma unroll
      for (int b=0;b<16;b++) acc = fmaf(g[8+b], w1s[b*64 + lane], acc);
      float hv = siluf(acc);
      float hp2 = __shfl_xor(hv, 1);
      if ((lane & 1) == 0) hidp[wib][lane>>1] = pack_h2(hv, hp2);
      float w0=0.f, w1v=0.f, w2v=0.f;
      #pragma unroll
      for (int q=0;q<8;q++){
        unsigned hq[4] = {hidp[wib][4*q], hidp[wib][4*q+1], hidp[wib][4*q+2], hidp[wib][4*q+3]};
        const uint4v* base = w2q + q*144;
        w0  = dot8f(base[lane],       hq, w0);
        w1v = dot8f(base[ 64 + lane], hq, w1v);
        w2v = dot8f(base[128 + v],    hq, w2v);
      }
      a0a += x0a*w0;
      a0b += x0b*w1v;
      a0c += w2v*dot;
    }
    float* a0 = A0 + (size_t)n*144;
    a0[lane] = a0a;
    a0[64 + lane] = a0b;
    if (lane < 16) a0[128 + lane] = a0c;
  }
}

// ---------------------------------------------------------------------------
// Final: out = A0@LO_lin2_0/12 + SCO   (N,4)
// ---------------------------------------------------------------------------
__global__ void k_final(const float* __restrict__ A0, const float* __restrict__ SCO,
                        const float* __restrict__ W, float* __restrict__ out){
  int i = blockIdx.x*blockDim.x + threadIdx.x;
  if (i >= N_NODES*4) return;
  int n = i >> 2, c = i & 3;
  const float* a0 = A0 + (size_t)n*144;
  float acc = 0.0f;
  for (int k=0;k<144;k++) acc += a0[k]*W[k*4 + c];
  out[i] = acc*(1.0f/12.0f) + SCO[i];
}

// ---------------------------------------------------------------------------
extern "C" void kernel_launch(void* const* d_in, const int* in_sizes, int n_in,
                              void* d_out, int out_size, void* d_ws, size_t ws_size,
                              hipStream_t stream) {
  const int*   x   = (const int*)  d_in[0];
  const int*   ei  = (const int*)  d_in[1];
  const float* ev  = (const float*)d_in[2];
  const float* emb = (const float*)d_in[3];
  const float* L1_lin1_0 = (const float*)d_in[4];
  const float* L1_W1     = (const float*)d_in[5];
  const float* L1_W2     = (const float*)d_in[6];
  const float* L1_lin2_0 = (const float*)d_in[7];
  const float* L1_lin2_1 = (const float*)d_in[8];
  const float* L1_sc_0   = (const float*)d_in[9];
  const float* L2_lin1_0 = (const float*)d_in[10];
  const float* L2_lin1_1 = (const float*)d_in[11];
  const float* L2_W1     = (const float*)d_in[12];
  const float* L2_W2     = (const float*)d_in[13];
  const float* L2_lin2_0 = (const float*)d_in[14];
  const float* L2_lin2_1 = (const float*)d_in[15];
  const float* L2_sc_0   = (const float*)d_in[16];
  const float* L2_sc_1   = (const float*)d_in[17];
  const float* LO_lin1_0 = (const float*)d_in[18];
  const float* LO_lin1_1 = (const float*)d_in[19];
  const float* LO_W1     = (const float*)d_in[20];
  const float* LO_W2     = (const float*)d_in[21];
  const float* LO_lin2_0 = (const float*)d_in[22];
  const float* LO_sc_0   = (const float*)d_in[23];
  float* out = (float*)d_out;

  int* cnt  = (int*)d_ws;                    // N
  int* off  = cnt  + N_NODES;                // N+1
  int* pos  = off  + N_NODES + 1;            // N
  int* perm = pos  + N_NODES;                // E
  int* srcs = perm + N_EDGES;                // E
  float* EG  = (float*)(srcs + N_EDGES);     // E*24
  float* X0  = EG  + (size_t)N_EDGES*24;     // N*128
  float* X1  = X0  + (size_t)N_NODES*128;    // N*48
  float* SC0 = X1  + (size_t)N_NODES*48;     // N*144
  float* SC1 = SC0 + (size_t)N_NODES*144;    // N*48
  float* A0  = SC1 + (size_t)N_NODES*48;     // N*144
  float* A1  = A0  + (size_t)N_NODES*144;    // N*528
  float* H0  = A1  + (size_t)N_NODES*528;    // N*128
  float* H1  = H0  + (size_t)N_NODES*128;    // N*48

  // CSR build
  hipMemsetAsync(cnt, 0, N_NODES*sizeof(int), stream);
  k_count  <<<(N_EDGES+255)/256, 256, 0, stream>>>(ei, cnt);
  k_scan   <<<1, 1024, 0, stream>>>(cnt, off, pos);
  k_scatter<<<(N_EDGES+255)/256, 256, 0, stream>>>(ei, pos, perm, srcs);
  k_geom   <<<(N_EDGES+255)/256, 256, 0, stream>>>(ev, perm, EG);

  k_node_l1<<<N_NODES/4, 256, 0, stream>>>(x, emb, L1_lin1_0, L1_sc_0, X0, SC0);
  k_edge_l1<<<1250, 256, 0, stream>>>(off, srcs, EG, L1_W1, L1_W2, X0, A0, A1);
  k_upd_l1<<<N_NODES/8, 256, 0, stream>>>(A0, A1, SC0, L1_lin2_0, L1_lin2_1, H0, H1);

  k_lin_l2<<<N_NODES/8, 384, 0, stream>>>(H0, H1, L2_sc_0, L2_sc_1, L2_lin1_0, L2_lin1_1,
                                          SC0, SC1, X0, X1);
  k_edge_l2<<<1250, 256, 0, stream>>>(off, srcs, EG, L2_W1, L2_W2, X0, X1, A0, A1);
  k_upd_l2<<<N_NODES/8, 256, 0, stream>>>(A0, A1, SC0, SC1, L2_lin2_0, L2_lin2_1, H0, H1);

  k_lin_lo<<<N_NODES/8, 256, 0, stream>>>(H0, H1, LO_sc_0, LO_lin1_0, LO_lin1_1, SC1, X0, X1);
  k_edge_lo<<<1250, 256, 0, stream>>>(off, srcs, EG, LO_W1, LO_W2, X0, X1, A0);
  k_final<<<(N_NODES*4+255)/256, 256, 0, stream>>>(A0, SC1, LO_lin2_0, out);
}